// Round 19
// baseline (227.912 us; speedup 1.0000x reference)
//
#include <hip/hip_runtime.h>
#include <hip/hip_bf16.h>
#include <math.h>

#define NSLICE 2048
#define NH 133     // output spatial size (int(128*1+4)+1)
#define NP 144     // padded to 9 tiles of 16
#define NT 576     // 9 waves per block
#define SPB 4      // slices per block -> 512 blocks = 2 persistent/CU
#define NBLK (NSLICE / SPB)

// LDS map (74,752 B; x2 = 149,504 <= 163,840 -> 2 blocks/CU, 18 waves):
//   [0, 65536)      X: 64 hf-granules x 1024 B.
//     staged:   fp32 half-frag hf at hf*1024 + lane*16 (gload_lds linear)
//     after cvt: bf16 frag f at f*2048 + lane*16 (in-place, even-hf regions)
//   [65536, 74752)  scratch: 9 waves x 1024 B (per-wave repack)
#define SCR  65536
#define LDSB 74752

typedef __attribute__((ext_vector_type(8))) short bf16x8;   // 8 bf16 = 4 VGPRs
typedef __attribute__((ext_vector_type(4))) float f32x4;

typedef __attribute__((address_space(3))) unsigned int  lds_u32;
typedef const __attribute__((address_space(1))) unsigned int glb_u32;

#define GLOAD_LDS16(gsrc, ldst) \
    __builtin_amdgcn_global_load_lds((glb_u32*)(gsrc), (lds_u32*)(ldst), 16, 0, 0)

__device__ __forceinline__ unsigned f2bf(float f) {
    __hip_bfloat16 h = __float2bfloat16(f);   // round-to-nearest-even
    union { __hip_bfloat16 b; unsigned short u; } c; c.b = h; return (unsigned)c.u;
}

// ---------------------------------------------------------------------------
// prep_M: combined (IDCT * mask * DCT) matrices, bf16, in workspace.
//   M[row, p] = sum_{u=0}^{127} D2[u,row] * mask[u] * D1[u,p]
// M1 emitted FRAGMENT-MAJOR (R10/R15-proven); M2 row-major.
// ---------------------------------------------------------------------------
__global__ void prep_M(const float* __restrict__ rw,
                       unsigned short* __restrict__ M1,
                       unsigned short* __restrict__ M2) {
    __shared__ float t1[512];
    __shared__ float t2[532];
    const int b   = blockIdx.x;        // 0..287
    const int m   = b / NP;            // 0 -> M1, 1 -> M2
    const int row = b - m * NP;        // 0..143
    const int p   = threadIdx.x;       // 0..127

    const float c1  = (float)(M_PI / 256.0);
    const float c2  = (float)(M_PI / 266.0);
    const float s1n = 0.125f;                  // sqrt(2/128)
    const float s10 = 0.08838834764831844f;    // s1n/sqrt(2)
    const float s2n = 0.12262786485246718f;    // sqrt(2/133)
    const float s20 = 0.08671099951921386f;    // s2n/sqrt(2)

    for (int k = p; k < 512; k += 128) t1[k] = cosf((float)k * c1) * s1n;
    for (int k = p; k < 532; k += 128) t2[k] = cosf((float)k * c2) * s2n;
    __syncthreads();

    float val = 0.0f;
    if (row < NH) {
        float r = rw[m];
        float minr = fmaxf((1.0f - 4.0f) / 128.0f, 0.0f);
        r = fminf(fmaxf(r, minr), 2.0f);
        const float crop = 128.0f * r;

        const int tp = 2 * p + 1;
        const int ti = 2 * row + 1;
        float acc = s10 * s20;        // u = 0 term (mask(0) == 1 since crop >= 0)
        int a1 = 0, a2 = 0;
        for (int u = 1; u < 128; ++u) {
            a1 = (a1 + tp) & 511;
            a2 += ti; if (a2 >= 532) a2 -= 532;
            float mask = fminf(fmaxf((4.0f + crop - (float)u) * 0.25f, 0.0f), 1.0f);
            acc = fmaf(t1[a1] * mask, t2[a2], acc);
        }
        val = acc;
    }
    const unsigned short v16 = (unsigned short)f2bf(val);
    if (m == 0) {
        const int it = row >> 4, rr = row & 15;
        const int k2 = p >> 5, gg = (p >> 3) & 3, e = p & 7;
        M1[(size_t)((it * 4 + k2) * 512 + (gg * 16 + rr) * 8 + e)] = v16;
    } else {
        M2[(size_t)row * 128 + p] = v16;
    }
}

// ---------------------------------------------------------------------------
// dct_resize: 512 persistent blocks (2/CU), 9 waves, 4 slices each.
// Two independent blocks per CU run out of phase -- one block's compute
// covers the other's staging/store stalls (the single-block R17/18 gap).
// Per slice (3 plain __syncthreads, no raw barriers, no counted vmcnt):
//   1. cvt own region IN PLACE: fp32 hf pair (2f,2f+1) -> bf16 frag f at
//      f*2048 (wave-local; read-before-write by dataflow)
//   2. __syncthreads
//   3. Stage A: 32 lane-contiguous b128 reads + 32 MFMA vs reg bm2 -> u2
//   4. __syncthreads  (all waves done reading X)
//   5. ISSUE_X(s+1): 8 fire-and-forget gload_lds/wave (fly through B)
//   6. per-wave repack (scr, in-wave DS ordering)
//   7. Stage B: 36 MFMA, A-frags from GLOBAL fragment-major M1 (L1/L2-hot,
//      R15-proven flat FETCH); guarded stores
//   8. __syncthreads  (built-in vmcnt(0): gloads + stores drained)
// ---------------------------------------------------------------------------
__global__ __launch_bounds__(NT, 4) void dct_resize(
        const float* __restrict__ x,
        const unsigned short* __restrict__ M1f,
        const unsigned short* __restrict__ M2,
        float* __restrict__ out) {
    __shared__ __align__(16) unsigned char lds[LDSB];

    const int tid  = threadIdx.x;
    const int w    = tid >> 6;      // wave 0..8
    const int lane = tid & 63;
    const int r    = lane & 15;     // fragment row/col index
    const int g    = lane >> 4;     // k-group 0..3

    const float* xbase = x   + (size_t)blockIdx.x * SPB * (128 * 128);
    float*       obase = out + (size_t)blockIdx.x * SPB * (NH * NH);

    const int j0 = w * 16;          // this wave's output-column tile

    // async staging of one slice; wave w owns hf in [8w, 8w+8)
    #define ISSUE_X(sl) do { if (w < 8) {                                      \
        const float* _xs = xbase + (size_t)(sl) * (128 * 128);                 \
        _Pragma("unroll")                                                      \
        for (int v = 0; v < 8; ++v) {                                          \
            const int hf = w * 8 + v;                                          \
            const int f_ = hf >> 1, h_ = hf & 1;                               \
            const int pt_ = f_ >> 2, k2_ = f_ & 3;                             \
            const float* _src = _xs + (size_t)(pt_ * 16 + r) * 128             \
                              + k2_ * 32 + g * 8 + h_ * 4;                     \
            GLOAD_LDS16(_src, lds + hf * 1024);   /* HW adds lane*16 */        \
        } } } while (0)

    // ---- prologue: slice 0 staging (async) + bm2 register fragments ----
    ISSUE_X(0);
    bf16x8 bm2[4];
    #pragma unroll
    for (int kk = 0; kk < 4; ++kk)
        bm2[kk] = *(const bf16x8*)(M2 + (size_t)(j0 + r) * 128 + kk * 32 + g * 8);
    __syncthreads();   // vmcnt(0) built in: Xbuf(slice 0) resident

    for (int s = 0; s < SPB; ++s) {
        // ---- 1. cvt own region IN PLACE: hf[8w..8w+8) -> frags [4w..4w+4) ----
        if (w < 8) {
            #pragma unroll
            for (int v = 0; v < 4; ++v) {
                const int f = 4 * w + v;
                const float4 lo = *(const float4*)(lds + (2 * f) * 1024 + lane * 16);
                const float4 hi = *(const float4*)(lds + (2 * f + 1) * 1024 + lane * 16);
                uint4 pkt;
                pkt.x = f2bf(lo.x) | (f2bf(lo.y) << 16);
                pkt.y = f2bf(lo.z) | (f2bf(lo.w) << 16);
                pkt.z = f2bf(hi.x) | (f2bf(hi.y) << 16);
                pkt.w = f2bf(hi.z) | (f2bf(hi.w) << 16);
                *(uint4*)(lds + f * 2048 + lane * 16) = pkt;   // in-place (even hf)
            }
        }
        __syncthreads();   // 2. converted frags visible to all waves

        // ---- 3. Stage A: T[j0+r][p] = sum_q X[p][q] * M2[j0+r][q] ----
        uint2 u2[8];
        #pragma unroll
        for (int pt = 0; pt < 8; ++pt) {
            f32x4 acc = {0.f, 0.f, 0.f, 0.f};
            #pragma unroll
            for (int kk = 0; kk < 4; ++kk) {
                bf16x8 a = *(const bf16x8*)(lds + (pt * 4 + kk) * 2048 + lane * 16);
                acc = __builtin_amdgcn_mfma_f32_16x16x32_bf16(a, bm2[kk], acc, 0, 0, 0);
            }
            u2[pt].x = f2bf(acc[0]) | (f2bf(acc[1]) << 16);
            u2[pt].y = f2bf(acc[2]) | (f2bf(acc[3]) << 16);
        }
        __syncthreads();   // 4. all waves done reading X

        // ---- 5. stage next slice (fire-and-forget; flies through B) ----
        if (s + 1 < SPB) ISSUE_X(s + 1);

        // ---- 6. per-wave repack: D layout (4-consec p) -> B-frag (8-consec p)
        unsigned char* scr = lds + SCR + w * 1024;
        bf16x8 bfrag[4];
        #pragma unroll
        for (int kk = 0; kk < 4; ++kk) {
            *(uint2*)(scr + (g)     * 128 + r * 8) = u2[2 * kk];
            *(uint2*)(scr + (4 + g) * 128 + r * 8) = u2[2 * kk + 1];
            const uint2 lo2 = *(const uint2*)(scr + (2 * g)     * 128 + r * 8);
            const uint2 hi2 = *(const uint2*)(scr + (2 * g + 1) * 128 + r * 8);
            union { uint4 u; bf16x8 b; } cv;
            cv.u = make_uint4(lo2.x, lo2.y, hi2.x, hi2.y);
            bfrag[kk] = cv.b;
        }

        // ---- 7. Stage B: out[i][j0+r] = sum_p M1[i][p] * T[j0+r][p] ----
        float* os = obase + (size_t)s * (NH * NH);
        const int jc = j0 + r;
        #pragma unroll
        for (int it = 0; it < 9; ++it) {
            f32x4 acc = {0.f, 0.f, 0.f, 0.f};
            #pragma unroll
            for (int kk = 0; kk < 4; ++kk) {
                bf16x8 a = *(const bf16x8*)(M1f + (size_t)(it * 4 + kk) * 512 + lane * 8);
                acc = __builtin_amdgcn_mfma_f32_16x16x32_bf16(a, bfrag[kk], acc, 0, 0, 0);
            }
            if (jc < NH) {
                #pragma unroll
                for (int q = 0; q < 4; ++q) {
                    const int i = it * 16 + g * 4 + q;
                    if (i < NH) os[(size_t)i * NH + jc] = acc[q];
                }
            }
        }

        __syncthreads();   // 8. drains gloads(s+1) + stores; X ready for cvt
    }
    #undef ISSUE_X
}

extern "C" void kernel_launch(void* const* d_in, const int* in_sizes, int n_in,
                              void* d_out, int out_size, void* d_ws, size_t ws_size,
                              hipStream_t stream) {
    const float* x  = (const float*)d_in[0];
    const float* rw = (const float*)d_in[1];
    float* outp = (float*)d_out;
    unsigned short* M1 = (unsigned short*)d_ws;     // 18432 ushorts, fragment-major
    unsigned short* M2 = M1 + 18432;                // 18432 ushorts, row-major

    prep_M<<<dim3(2 * NP), dim3(128), 0, stream>>>(rw, M1, M2);
    dct_resize<<<dim3(NBLK), dim3(NT), 0, stream>>>(x, M1, M2, outp);
}

// Round 20
// 89.850 us; speedup vs baseline: 2.5366x; 2.5366x over previous
//
#include <hip/hip_runtime.h>
#include <hip/hip_bf16.h>
#include <math.h>

#define NSLICE 2048
#define NH 133     // output spatial size (int(128*1+4)+1)
#define NP 144     // padded to 9 tiles of 16
#define NT 576     // 9 waves per block
#define SPB 4      // slices per block -> 512 blocks = 2 persistent/CU
#define NBLK (NSLICE / SPB)
#define NSTRIPS (SPB * 4)   // 16 strips of 2 p-tiles (8 frags) per block

// LDS map (78,848 B; x2 = 157,696 <= 163,840 -> 2 blocks/CU, 18 waves):
//   [0, 16384)      strip buffer B0 (16 hf-granules x 1024 B fp32; after
//                   in-place cvt: bf16 frag fl at fl*2048, even granules)
//   [16384, 32768)  strip buffer B1
//   [32768, 69632)  M1_fm bf16 fragment-major: 36 frags x 1024 B
//   [69632, 78848)  scratch: 9 waves x 1024 B (per-wave repack)
#define M1B  32768
#define SCR  69632
#define LDSB 78848

typedef __attribute__((ext_vector_type(8))) short bf16x8;   // 8 bf16 = 4 VGPRs
typedef __attribute__((ext_vector_type(4))) float f32x4;

typedef __attribute__((address_space(3))) unsigned int  lds_u32;
typedef const __attribute__((address_space(1))) unsigned int glb_u32;

#define GLOAD_LDS16(gsrc, ldst) \
    __builtin_amdgcn_global_load_lds((glb_u32*)(gsrc), (lds_u32*)(ldst), 16, 0, 0)

#define VMW0  asm volatile("s_waitcnt vmcnt(0)" ::: "memory")
#define VMW36 asm volatile("s_waitcnt vmcnt(36)" ::: "memory")
// raw barrier (lgkm drain + s_barrier), fenced; vmcnt NOT drained
#define BAR() do { __builtin_amdgcn_sched_barrier(0); \
                   asm volatile("s_waitcnt lgkmcnt(0)" ::: "memory"); \
                   __builtin_amdgcn_s_barrier(); \
                   __builtin_amdgcn_sched_barrier(0); } while (0)

__device__ __forceinline__ unsigned f2bf(float f) {
    __hip_bfloat16 h = __float2bfloat16(f);   // round-to-nearest-even
    union { __hip_bfloat16 b; unsigned short u; } c; c.b = h; return (unsigned)c.u;
}

// ---------------------------------------------------------------------------
// prep_M: combined (IDCT * mask * DCT) matrices, bf16, in workspace.
//   M[row, p] = sum_{u=0}^{127} D2[u,row] * mask[u] * D1[u,p]
// M1 emitted FRAGMENT-MAJOR (R10-proven); M2 row-major.
// ---------------------------------------------------------------------------
__global__ void prep_M(const float* __restrict__ rw,
                       unsigned short* __restrict__ M1,
                       unsigned short* __restrict__ M2) {
    __shared__ float t1[512];
    __shared__ float t2[532];
    const int b   = blockIdx.x;        // 0..287
    const int m   = b / NP;            // 0 -> M1, 1 -> M2
    const int row = b - m * NP;        // 0..143
    const int p   = threadIdx.x;       // 0..127

    const float c1  = (float)(M_PI / 256.0);
    const float c2  = (float)(M_PI / 266.0);
    const float s1n = 0.125f;                  // sqrt(2/128)
    const float s10 = 0.08838834764831844f;    // s1n/sqrt(2)
    const float s2n = 0.12262786485246718f;    // sqrt(2/133)
    const float s20 = 0.08671099951921386f;    // s2n/sqrt(2)

    for (int k = p; k < 512; k += 128) t1[k] = cosf((float)k * c1) * s1n;
    for (int k = p; k < 532; k += 128) t2[k] = cosf((float)k * c2) * s2n;
    __syncthreads();

    float val = 0.0f;
    if (row < NH) {
        float r = rw[m];
        float minr = fmaxf((1.0f - 4.0f) / 128.0f, 0.0f);
        r = fminf(fmaxf(r, minr), 2.0f);
        const float crop = 128.0f * r;

        const int tp = 2 * p + 1;
        const int ti = 2 * row + 1;
        float acc = s10 * s20;        // u = 0 term (mask(0) == 1 since crop >= 0)
        int a1 = 0, a2 = 0;
        for (int u = 1; u < 128; ++u) {
            a1 = (a1 + tp) & 511;
            a2 += ti; if (a2 >= 532) a2 -= 532;
            float mask = fminf(fmaxf((4.0f + crop - (float)u) * 0.25f, 0.0f), 1.0f);
            acc = fmaf(t1[a1] * mask, t2[a2], acc);
        }
        val = acc;
    }
    const unsigned short v16 = (unsigned short)f2bf(val);
    if (m == 0) {
        const int it = row >> 4, rr = row & 15;
        const int k2 = p >> 5, gg = (p >> 3) & 3, e = p & 7;
        M1[(size_t)((it * 4 + k2) * 512 + (gg * 16 + rr) * 8 + e)] = v16;
    } else {
        M2[(size_t)row * 128 + p] = v16;
    }
}

// ---------------------------------------------------------------------------
// dct_resize: 512 persistent blocks (2/CU), 9 waves, 4 slices each.
// X streams in 16 KB strips (2 p-tiles = 8 frags) through 2 buffers;
// in-place cvt (fp32 hf pair -> bf16 frag, wave-local, R19-proven);
// M1_fm LDS-resident (persistent blocks REQUIRE this -- R19 showed global
// M1 thrashes L2 at persistent-block access intervals). All LDS access is
// lane-contiguous fragment-major (proven ~300K conflicts).
// Per strip n: VMW(t==0 ? 36 : 0) ; BAR ; ISSUE(n+1) ; cvt own frag ;
//              BAR ; stage A p-tiles 2t, 2t+1 -> u2.
// Per slice:   repack (per-wave scratch) ; stage B (M1_fm) ; 36 stores.
// vmcnt per-wave in-order queue: strip-0 wait vmcnt(36) skips the stores
// enqueued behind the gloads; strips 1-3 wait vmcnt(0) (stores drained by
// then). The 2nd block/CU covers barrier/staging stalls.
// ---------------------------------------------------------------------------
__global__ __launch_bounds__(NT, 4) void dct_resize(
        const float* __restrict__ x,
        const unsigned short* __restrict__ M1f,
        const unsigned short* __restrict__ M2,
        float* __restrict__ out) {
    __shared__ __align__(16) unsigned char lds[LDSB];

    const int tid  = threadIdx.x;
    const int w    = tid >> 6;      // wave 0..8
    const int lane = tid & 63;
    const int r    = lane & 15;     // fragment row/col index
    const int g    = lane >> 4;     // k-group 0..3

    const float* xbase = x   + (size_t)blockIdx.x * SPB * (128 * 128);
    float*       obase = out + (size_t)blockIdx.x * SPB * (NH * NH);

    const int j0 = w * 16;          // this wave's output-column tile

    // strip n covers p-tiles 2*(n&3), 2*(n&3)+1 of slice n>>2.
    // wave w (<8) owns frag fl = w (pt-parity w>>2, kk = w&3): 2 gloads.
    #define ISSUE_STRIP(n_) do { if (w < 8 && (n_) < NSTRIPS) {                \
        const float* _xs = xbase + (size_t)((n_) >> 2) * (128 * 128);          \
        const int pt_ = 2 * ((n_) & 3) + (w >> 2);                             \
        const float* s0 = _xs + (size_t)(pt_ * 16 + r) * 128                   \
                        + (w & 3) * 32 + g * 8;                                \
        GLOAD_LDS16(s0,     lds + ((n_) & 1) * 16384 + (2 * w) * 1024);        \
        GLOAD_LDS16(s0 + 4, lds + ((n_) & 1) * 16384 + (2 * w + 1) * 1024);    \
    } } while (0)

    // ---- prologue: bm2 regs (queue cleaned), M1_fm copy, strip 0 ----
    bf16x8 bm2[4];
    #pragma unroll
    for (int kk = 0; kk < 4; ++kk)
        bm2[kk] = *(const bf16x8*)(M2 + (size_t)(j0 + r) * 128 + kk * 32 + g * 8);
    asm volatile("" :: "v"(bm2[0]), "v"(bm2[1]), "v"(bm2[2]), "v"(bm2[3]));
    VMW0;                         // bm2 retired; vm queue clean
    __builtin_amdgcn_sched_barrier(0);

    #pragma unroll
    for (int v = 0; v < 4; ++v)
        GLOAD_LDS16(M1f + (size_t)(v * NT + tid) * 8,
                    lds + M1B + (v * NT + tid) * 16);
    ISSUE_STRIP(0);
    __syncthreads();              // drains all: M1_fm + strip 0 resident

    for (int s = 0; s < SPB; ++s) {
        uint2 u2[8];
        #pragma unroll
        for (int t = 0; t < 4; ++t) {
            const int n = s * 4 + t;
            if (t == 0) { VMW36; } else { VMW0; }   // strip n landed
            BAR();                                  // + all waves done with B[(n+1)&1]'s old strip
            ISSUE_STRIP(n + 1);                     // fire-and-forget

            // ---- in-place cvt of own frag (wave-local; read then write) ----
            unsigned char* B = lds + (n & 1) * 16384;
            if (w < 8) {
                const float4 lo = *(const float4*)(B + (2 * w) * 1024 + lane * 16);
                const float4 hi = *(const float4*)(B + (2 * w + 1) * 1024 + lane * 16);
                uint4 pkt;
                pkt.x = f2bf(lo.x) | (f2bf(lo.y) << 16);
                pkt.y = f2bf(lo.z) | (f2bf(lo.w) << 16);
                pkt.z = f2bf(hi.x) | (f2bf(hi.y) << 16);
                pkt.w = f2bf(hi.z) | (f2bf(hi.w) << 16);
                *(uint4*)(B + w * 2048 + lane * 16) = pkt;
            }
            BAR();                                  // cvt visible to all waves

            // ---- Stage A on strip n: p-tiles 2t, 2t+1 ----
            #pragma unroll
            for (int d = 0; d < 2; ++d) {
                f32x4 acc = {0.f, 0.f, 0.f, 0.f};
                #pragma unroll
                for (int kk = 0; kk < 4; ++kk) {
                    bf16x8 a = *(const bf16x8*)(B + (d * 4 + kk) * 2048 + lane * 16);
                    acc = __builtin_amdgcn_mfma_f32_16x16x32_bf16(a, bm2[kk], acc, 0, 0, 0);
                }
                const int pt = 2 * t + d;
                u2[pt].x = f2bf(acc[0]) | (f2bf(acc[1]) << 16);
                u2[pt].y = f2bf(acc[2]) | (f2bf(acc[3]) << 16);
            }
        }

        // ---- per-wave repack: D layout (4-consec p) -> B-frag (8-consec p)
        // In-wave DS ordering -> barrier-free (R4/R10-proven).
        unsigned char* scr = lds + SCR + w * 1024;
        bf16x8 bfrag[4];
        #pragma unroll
        for (int kk = 0; kk < 4; ++kk) {
            *(uint2*)(scr + (g)     * 128 + r * 8) = u2[2 * kk];
            *(uint2*)(scr + (4 + g) * 128 + r * 8) = u2[2 * kk + 1];
            const uint2 lo2 = *(const uint2*)(scr + (2 * g)     * 128 + r * 8);
            const uint2 hi2 = *(const uint2*)(scr + (2 * g + 1) * 128 + r * 8);
            union { uint4 u; bf16x8 b; } cv;
            cv.u = make_uint4(lo2.x, lo2.y, hi2.x, hi2.y);
            bfrag[kk] = cv.b;
        }

        // ---- Stage B: out[i][j0+r] = sum_p M1[i][p] * T[j0+r][p] ----
        float* os = obase + (size_t)s * (NH * NH);
        const int jc = j0 + r;
        #pragma unroll
        for (int it = 0; it < 9; ++it) {
            f32x4 acc = {0.f, 0.f, 0.f, 0.f};
            #pragma unroll
            for (int kk = 0; kk < 4; ++kk) {
                bf16x8 a = *(const bf16x8*)(lds + M1B + (it * 4 + kk) * 1024 + lane * 16);
                acc = __builtin_amdgcn_mfma_f32_16x16x32_bf16(a, bfrag[kk], acc, 0, 0, 0);
            }
            if (jc < NH) {
                #pragma unroll
                for (int q = 0; q < 4; ++q) {
                    const int i = it * 16 + g * 4 + q;
                    if (i < NH) os[(size_t)i * NH + jc] = acc[q];
                }
            }
        }
        // stores (36/wave) stay in flight; next slice's strip-0 VMW36 skips
        // them, and they drain before the strip-1 VMW0.
    }
    #undef ISSUE_STRIP
}

extern "C" void kernel_launch(void* const* d_in, const int* in_sizes, int n_in,
                              void* d_out, int out_size, void* d_ws, size_t ws_size,
                              hipStream_t stream) {
    const float* x  = (const float*)d_in[0];
    const float* rw = (const float*)d_in[1];
    float* outp = (float*)d_out;
    unsigned short* M1 = (unsigned short*)d_ws;     // 18432 ushorts, fragment-major
    unsigned short* M2 = M1 + 18432;                // 18432 ushorts, row-major

    prep_M<<<dim3(2 * NP), dim3(128), 0, stream>>>(rw, M1, M2);
    dct_resize<<<dim3(NBLK), dim3(NT), 0, stream>>>(x, M1, M2, outp);
}

// Round 21
// 70.645 us; speedup vs baseline: 3.2262x; 1.2719x over previous
//
#include <hip/hip_runtime.h>
#include <hip/hip_bf16.h>
#include <math.h>

#define NSLICE 2048
#define NH 133     // output spatial size (int(128*1+4)+1)
#define NP 144     // padded to 9 tiles of 16
#define NT 576     // 9 waves per block
#define SPB 8      // slices per block -> 256 blocks = 1/CU, ONE generation
#define NBLK (NSLICE / SPB)

// LDS map (144,384 B -> 1 block/CU):
//   [0, 65536)        Xbuf fp32, HALF-FRAGMENT-major: 64 hf x 1024 B
//   [65536, 98304)    X_fm bf16 fragment-major: 32 frags x 1024 B
//   [98304, 135168)   M1_fm bf16 fragment-major: 36 frags x 1024 B
//   [135168, 144384)  scratch: 9 waves x 1024 B (per-wave repack)
#define XFM  65536
#define M1B  98304
#define SCR  135168
#define LDSB 144384

typedef __attribute__((ext_vector_type(8))) short bf16x8;   // 8 bf16 = 4 VGPRs
typedef __attribute__((ext_vector_type(4))) float f32x4;

typedef __attribute__((address_space(3))) unsigned int  lds_u32;
typedef const __attribute__((address_space(1))) unsigned int glb_u32;

#define GLOAD_LDS16(gsrc, ldst) \
    __builtin_amdgcn_global_load_lds((glb_u32*)(gsrc), (lds_u32*)(ldst), 16, 0, 0)

#define LGKM0 asm volatile("s_waitcnt lgkmcnt(0)" ::: "memory")
// end-of-slice wait: per-wave queue = [8 gloads(s+1)][36 stores] -> vmcnt(36)
// retires exactly the gloads; stores drain in background. (Wave 8 issues
// neither gloads nor a full store set and passes trivially -- safe.)
#define VMW36 asm volatile("s_waitcnt vmcnt(36)" ::: "memory")
// raw barrier, fenced; vmcnt deliberately NOT drained (stores stay in flight)
#define BAR() do { __builtin_amdgcn_sched_barrier(0); \
                   asm volatile("s_waitcnt lgkmcnt(0)" ::: "memory"); \
                   __builtin_amdgcn_s_barrier(); \
                   __builtin_amdgcn_sched_barrier(0); } while (0)

__device__ __forceinline__ unsigned f2bf(float f) {
    __hip_bfloat16 h = __float2bfloat16(f);   // round-to-nearest-even
    union { __hip_bfloat16 b; unsigned short u; } c; c.b = h; return (unsigned)c.u;
}

// ---------------------------------------------------------------------------
// prep_M: combined (IDCT * mask * DCT) matrices, bf16, in workspace.
//   M[row, p] = sum_{u=0}^{127} D2[u,row] * mask[u] * D1[u,p]
// M1 emitted FRAGMENT-MAJOR (R10-proven); M2 row-major.
// ---------------------------------------------------------------------------
__global__ void prep_M(const float* __restrict__ rw,
                       unsigned short* __restrict__ M1,
                       unsigned short* __restrict__ M2) {
    __shared__ float t1[512];
    __shared__ float t2[532];
    const int b   = blockIdx.x;        // 0..287
    const int m   = b / NP;            // 0 -> M1, 1 -> M2
    const int row = b - m * NP;        // 0..143
    const int p   = threadIdx.x;       // 0..127

    const float c1  = (float)(M_PI / 256.0);
    const float c2  = (float)(M_PI / 266.0);
    const float s1n = 0.125f;                  // sqrt(2/128)
    const float s10 = 0.08838834764831844f;    // s1n/sqrt(2)
    const float s2n = 0.12262786485246718f;    // sqrt(2/133)
    const float s20 = 0.08671099951921386f;    // s2n/sqrt(2)

    for (int k = p; k < 512; k += 128) t1[k] = cosf((float)k * c1) * s1n;
    for (int k = p; k < 532; k += 128) t2[k] = cosf((float)k * c2) * s2n;
    __syncthreads();

    float val = 0.0f;
    if (row < NH) {
        float r = rw[m];
        float minr = fmaxf((1.0f - 4.0f) / 128.0f, 0.0f);
        r = fminf(fmaxf(r, minr), 2.0f);
        const float crop = 128.0f * r;

        const int tp = 2 * p + 1;
        const int ti = 2 * row + 1;
        float acc = s10 * s20;        // u = 0 term (mask(0) == 1 since crop >= 0)
        int a1 = 0, a2 = 0;
        for (int u = 1; u < 128; ++u) {
            a1 = (a1 + tp) & 511;
            a2 += ti; if (a2 >= 532) a2 -= 532;
            float mask = fminf(fmaxf((4.0f + crop - (float)u) * 0.25f, 0.0f), 1.0f);
            acc = fmaf(t1[a1] * mask, t2[a2], acc);
        }
        val = acc;
    }
    const unsigned short v16 = (unsigned short)f2bf(val);
    if (m == 0) {
        const int it = row >> 4, rr = row & 15;
        const int k2 = p >> 5, gg = (p >> 3) & 3, e = p & 7;
        M1[(size_t)((it * 4 + k2) * 512 + (gg * 16 + rr) * 8 + e)] = v16;
    } else {
        M2[(size_t)row * 128 + p] = v16;
    }
}

// ---------------------------------------------------------------------------
// dct_resize: 256 persistent blocks (1/CU), 9 waves, 8 slices each.
// R18 structure (best measured: 70.5 us wall) + micro-cuts:
//   - store guards folded at compile time (i<NH provably true for it<8)
//   - s_setprio(1) around the MFMA clusters (T5; waves drift between
//     barriers, mild role diversity)
// Per slice: cvt own region (Xbuf->X_fm, wave-local) ; LGKM0 ;
//   issue gloads(s+1) ; BAR ; Stage A ; repack ; Stage B (36 stores) ;
//   VMW36 (gloads retired, stores keep flying) ; BAR.
// ---------------------------------------------------------------------------
__global__ __launch_bounds__(NT, 2) void dct_resize(
        const float* __restrict__ x,
        const unsigned short* __restrict__ M1f,
        const unsigned short* __restrict__ M2,
        float* __restrict__ out) {
    __shared__ __align__(16) unsigned char lds[LDSB];

    const int tid  = threadIdx.x;
    const int w    = tid >> 6;      // wave 0..8
    const int lane = tid & 63;
    const int r    = lane & 15;     // fragment row/col index
    const int g    = lane >> 4;     // k-group 0..3

    const float* xbase = x   + (size_t)blockIdx.x * SPB * (128 * 128);
    float*       obase = out + (size_t)blockIdx.x * SPB * (NH * NH);

    const int j0 = w * 16;          // this wave's output-column tile

    // async staging of one slice into Xbuf; wave w owns hf in [8w, 8w+8)
    #define ISSUE_X(sl) do { if (w < 8) {                                      \
        const float* _xs = xbase + (size_t)(sl) * (128 * 128);                 \
        _Pragma("unroll")                                                      \
        for (int v = 0; v < 8; ++v) {                                          \
            const int hf = w * 8 + v;                                          \
            const int f_ = hf >> 1, h_ = hf & 1;                               \
            const int pt_ = f_ >> 2, k2_ = f_ & 3;                             \
            const float* _src = _xs + (size_t)(pt_ * 16 + r) * 128             \
                              + k2_ * 32 + g * 8 + h_ * 4;                     \
            GLOAD_LDS16(_src, lds + hf * 1024);   /* HW adds lane*16 */        \
        } } } while (0)

    // ---- prologue: M1_fm copy + slice 0 staging (all async) + bm2 regs ----
    #pragma unroll
    for (int v = 0; v < 4; ++v)
        GLOAD_LDS16(M1f + (size_t)(v * NT + tid) * 8,
                    lds + M1B + (v * NT + tid) * 16);
    ISSUE_X(0);

    bf16x8 bm2[4];
    #pragma unroll
    for (int kk = 0; kk < 4; ++kk)
        bm2[kk] = *(const bf16x8*)(M2 + (size_t)(j0 + r) * 128 + kk * 32 + g * 8);

    __syncthreads();   // vmcnt(0) built in: M1_fm + Xbuf(slice 0) resident

    for (int s = 0; s < SPB; ++s) {
        // ---- cvt OWN region: Xbuf hf[8w..8w+8) -> X_fm frags [4w..4w+4) ----
        if (w < 8) {
            #pragma unroll
            for (int v = 0; v < 4; ++v) {
                const int f = 4 * w + v;
                const float4 lo = *(const float4*)(lds + (2 * f) * 1024 + lane * 16);
                const float4 hi = *(const float4*)(lds + (2 * f + 1) * 1024 + lane * 16);
                uint4 pkt;
                pkt.x = f2bf(lo.x) | (f2bf(lo.y) << 16);
                pkt.y = f2bf(lo.z) | (f2bf(lo.w) << 16);
                pkt.z = f2bf(hi.x) | (f2bf(hi.y) << 16);
                pkt.w = f2bf(hi.z) | (f2bf(hi.w) << 16);
                *(uint4*)(lds + XFM + f * 1024 + lane * 16) = pkt;
            }
        }
        // own cvt reads complete -> safe to let HW overwrite own Xbuf region
        LGKM0;
        if (s + 1 < SPB) ISSUE_X(s + 1);   // fire-and-forget

        BAR();   // all X_fm writes visible to all waves

        // ---- Stage A: T[j0+r][p] = sum_q X[p][q] * M2[j0+r][q] ----
        uint2 u2[8];
        __builtin_amdgcn_s_setprio(1);
        #pragma unroll
        for (int pt = 0; pt < 8; ++pt) {
            f32x4 acc = {0.f, 0.f, 0.f, 0.f};
            #pragma unroll
            for (int kk = 0; kk < 4; ++kk) {
                bf16x8 a = *(const bf16x8*)(lds + XFM + (pt * 4 + kk) * 1024 + lane * 16);
                acc = __builtin_amdgcn_mfma_f32_16x16x32_bf16(a, bm2[kk], acc, 0, 0, 0);
            }
            u2[pt].x = f2bf(acc[0]) | (f2bf(acc[1]) << 16);
            u2[pt].y = f2bf(acc[2]) | (f2bf(acc[3]) << 16);
        }
        __builtin_amdgcn_s_setprio(0);

        // ---- per-wave repack: D layout (4-consec p) -> B-frag (8-consec p)
        // In-wave DS ordering -> barrier-free (R4/R10-proven).
        unsigned char* scr = lds + SCR + w * 1024;
        bf16x8 bfrag[4];
        #pragma unroll
        for (int kk = 0; kk < 4; ++kk) {
            *(uint2*)(scr + (g)     * 128 + r * 8) = u2[2 * kk];
            *(uint2*)(scr + (4 + g) * 128 + r * 8) = u2[2 * kk + 1];
            const uint2 lo2 = *(const uint2*)(scr + (2 * g)     * 128 + r * 8);
            const uint2 hi2 = *(const uint2*)(scr + (2 * g + 1) * 128 + r * 8);
            union { uint4 u; bf16x8 b; } cv;
            cv.u = make_uint4(lo2.x, lo2.y, hi2.x, hi2.y);
            bfrag[kk] = cv.b;
        }

        // ---- Stage B: out[i][j0+r] = sum_p M1[i][p] * T[j0+r][p] ----
        float* os = obase + (size_t)s * (NH * NH);
        const int jc = j0 + r;
        const bool jok = jc < NH;            // hoisted (false only in wave 8)
        __builtin_amdgcn_s_setprio(1);
        #pragma unroll
        for (int it = 0; it < 9; ++it) {
            f32x4 acc = {0.f, 0.f, 0.f, 0.f};
            #pragma unroll
            for (int kk = 0; kk < 4; ++kk) {
                bf16x8 a = *(const bf16x8*)(lds + M1B + (it * 4 + kk) * 1024 + lane * 16);
                acc = __builtin_amdgcn_mfma_f32_16x16x32_bf16(a, bfrag[kk], acc, 0, 0, 0);
            }
            if (jok) {
                #pragma unroll
                for (int q = 0; q < 4; ++q) {
                    const int i = it * 16 + g * 4 + q;
                    // it<8 folds the guard at compile time (max i = 127 < NH)
                    if (it < 8 || i < NH) os[(size_t)i * NH + jc] = acc[q];
                }
            }
        }
        __builtin_amdgcn_s_setprio(0);

        // ---- slice boundary: retire ONLY the gloads; stores keep flying ----
        VMW36;   // queue: [8 gloads][36 stores] -> oldest 8 retired
        BAR();   // X_fm(s) reads done everywhere; next cvt may overwrite
    }
    #undef ISSUE_X
}

extern "C" void kernel_launch(void* const* d_in, const int* in_sizes, int n_in,
                              void* d_out, int out_size, void* d_ws, size_t ws_size,
                              hipStream_t stream) {
    const float* x  = (const float*)d_in[0];
    const float* rw = (const float*)d_in[1];
    float* outp = (float*)d_out;
    unsigned short* M1 = (unsigned short*)d_ws;     // 18432 ushorts, fragment-major
    unsigned short* M2 = M1 + 18432;                // 18432 ushorts, row-major

    prep_M<<<dim3(2 * NP), dim3(128), 0, stream>>>(rw, M1, M2);
    dct_resize<<<dim3(NBLK), dim3(NT), 0, stream>>>(x, M1, M2, outp);
}